// Round 4
// baseline (484.923 us; speedup 1.0000x reference)
//
#include <hip/hip_runtime.h>
#include <hip/hip_cooperative_groups.h>

namespace cg = cooperative_groups;

// DKNN via NeuralSort relaxation — round 7 (single cooperative dispatch).
// query [32,128] f32, neighbors [1024,128] f32, gumbel [2,32,1024] f32.
// out [2,32,1024] f32 = sum of first K=16 rows of relaxed perm matrix.
//
// Numerics FROZEN (absmax pinned at 0.0234375, bf16 compare). Phase bodies
// are the exact R6 kernels (all bit-proven):
//   phase 1 = k_scores body (256 of 1024 blocks, b&3==0)
//   phase 2 = k_bsum body   (all 1024 blocks, same decode)
//   phase 3 = k_soft body   (64 blocks, b&15==0)
// joined by threadfence + grid.sync(). No accumulation chain reordered =>
// bitwise-identical output.
//
// R6 post-mortem: kernel work ~11 us, poison-fill floor ~40 us, residual
// ~25 us = inter-dispatch gaps (~8 us per dependent boundary). This round
// removes two boundaries by fusing all three kernels into one cooperative
// launch; grid syncs cost ~2-4 us each.
//
// Occupancy contract for cooperative launch: __launch_bounds__(256,4)
// => <=128 VGPR => 4 blocks/CU => 1024 blocks co-resident on 256 CUs.
// LDS/block = qs(1K)+ss(2K)+red(0.5K) ~3.5 KB — not binding.

constexpr int NN = 1024;   // neighbors
constexpr int ND = 128;    // dims
constexpr int NP = 64;     // samples(2) * queries(32)
constexpr int KTOP = 16;

__global__ __launch_bounds__(256, 4) void k_fused(
    const float* __restrict__ q, const float* __restrict__ nb,
    const float* __restrict__ gum, double* __restrict__ s_out,
    double* __restrict__ Bq, float* __restrict__ out) {
  cg::grid_group grid = cg::this_grid();
  int b = blockIdx.x;
  int tid = threadIdx.x;
  __shared__ double qs[ND];
  __shared__ double ss[256];
  __shared__ float redm[KTOP][4];
  __shared__ float redz[KTOP][4];

  // ---------------- phase 1: scores (exact R6 k_scores body) -------------
  if ((b & 3) == 0) {
    int b256 = b >> 2;            // 0..255, same unit space as R6 k_scores
    int p = b256 >> 2, chunk = b256 & 3;
    int m = p & 31;
    if (tid < ND) qs[tid] = (double)q[m * ND + tid];
    __syncthreads();
    int j = chunk * 256 + tid;
    const float4* nrow = (const float4*)(nb + (size_t)j * ND);
    double a0 = 0.0, a1 = 0.0, a2 = 0.0, a3 = 0.0;
#pragma unroll
    for (int d4 = 0; d4 < ND / 4; ++d4) {
      float4 n4 = nrow[d4];
      double d0 = qs[d4 * 4 + 0] - (double)n4.x;
      double d1 = qs[d4 * 4 + 1] - (double)n4.y;
      double d2 = qs[d4 * 4 + 2] - (double)n4.z;
      double d3 = qs[d4 * 4 + 3] - (double)n4.w;
      a0 += d0 * d0; a1 += d1 * d1; a2 += d2 * d2; a3 += d3 * d3;
    }
    s_out[(size_t)p * NN + j] =
        (double)gum[(size_t)p * NN + j] - ((a0 + a1) + (a2 + a3));
  }
  __threadfence();
  grid.sync();

  // ---------------- phase 2: B quarter-sums (exact R6 k_bsum body) -------
  {
    int p = b >> 4, jc = (b >> 2) & 3, iq = b & 3;
    ss[tid] = s_out[(size_t)p * NN + iq * 256 + tid];
    __syncthreads();
    double sj = s_out[(size_t)p * NN + jc * 256 + tid];
    double a0 = 0.0, a1 = 0.0, a2 = 0.0, a3 = 0.0;
#pragma unroll 4
    for (int i = 0; i < 256; i += 4) {
      a0 += fabs(sj - ss[i + 0]);
      a1 += fabs(sj - ss[i + 1]);
      a2 += fabs(sj - ss[i + 2]);
      a3 += fabs(sj - ss[i + 3]);
    }
    Bq[((size_t)iq * NP + p) * NN + jc * 256 + tid] = (a0 + a1) + (a2 + a3);
  }
  __threadfence();
  grid.sync();

  // ---------------- phase 3: softmax-topk (exact R6 k_soft body) ---------
  if ((b & 15) != 0) return;
  {
    int p = b >> 4;               // 0..63
    int wave = tid >> 6, lane = tid & 63;
    const size_t QS = (size_t)NP * NN;
    size_t base = (size_t)p * NN;
    double sj[4], bj[4];
    float acc[4];
#pragma unroll
    for (int k = 0; k < 4; ++k) {
      size_t idx = base + tid + k * 256;
      sj[k] = s_out[idx];
      bj[k] = (Bq[idx] + Bq[QS + idx]) + (Bq[2 * QS + idx] + Bq[3 * QS + idx]);
      acc[k] = 0.f;
    }
    // pass 1: per-thread maxes for all 16 ranks, one batched reduction
    float mx[KTOP];
#pragma unroll
    for (int r = 0; r < KTOP; ++r) {
      double cr = (double)(1023 - 2 * r);
      float mv = -3.4e38f;
#pragma unroll
      for (int k = 0; k < 4; ++k) mv = fmaxf(mv, (float)fma(cr, sj[k], -bj[k]));
      mx[r] = mv;
    }
#pragma unroll
    for (int off = 32; off; off >>= 1) {
#pragma unroll
      for (int r = 0; r < KTOP; ++r)
        mx[r] = fmaxf(mx[r], __shfl_down(mx[r], off, 64));
    }
    if (lane == 0) {
#pragma unroll
      for (int r = 0; r < KTOP; ++r) redm[r][wave] = mx[r];
    }
    __syncthreads();
    float mf[KTOP];
#pragma unroll
    for (int r = 0; r < KTOP; ++r)
      mf[r] = fmaxf(fmaxf(redm[r][0], redm[r][1]),
                    fmaxf(redm[r][2], redm[r][3]));
    // pass 2: per-thread Z partials for all 16 ranks, one batched reduction
    float zz[KTOP];
#pragma unroll
    for (int r = 0; r < KTOP; ++r) {
      double cr = (double)(1023 - 2 * r);
      double md = (double)mf[r];
      float z = 0.f;
#pragma unroll
      for (int k = 0; k < 4; ++k)
        z += __expf((float)(fma(cr, sj[k], -bj[k]) - md));
      zz[r] = z;
    }
#pragma unroll
    for (int off = 32; off; off >>= 1) {
#pragma unroll
      for (int r = 0; r < KTOP; ++r) zz[r] += __shfl_down(zz[r], off, 64);
    }
    if (lane == 0) {
#pragma unroll
      for (int r = 0; r < KTOP; ++r) redz[r][wave] = zz[r];
    }
    __syncthreads();
    // pass 3: accumulate in original r order (bitwise-identical acc)
#pragma unroll
    for (int r = 0; r < KTOP; ++r) {
      double cr = (double)(1023 - 2 * r);
      double md = (double)mf[r];
      float iZ = 1.0f / ((redz[r][0] + redz[r][1]) + (redz[r][2] + redz[r][3]));
#pragma unroll
      for (int k = 0; k < 4; ++k)
        acc[k] += __expf((float)(fma(cr, sj[k], -bj[k]) - md)) * iZ;
    }
#pragma unroll
    for (int k = 0; k < 4; ++k) out[base + tid + k * 256] = acc[k];
  }
}

// ---------------- fallback kernels (exact R6, used only if coop fails) ----
__global__ __launch_bounds__(256) void k_scores(const float* __restrict__ q,
                                                const float* __restrict__ nb,
                                                const float* __restrict__ gum,
                                                double* __restrict__ s_out) {
  int b = blockIdx.x;
  int p = b >> 2, chunk = b & 3;
  int m = p & 31;
  __shared__ double qs[ND];
  int tid = threadIdx.x;
  if (tid < ND) qs[tid] = (double)q[m * ND + tid];
  __syncthreads();
  int j = chunk * 256 + tid;
  const float4* nrow = (const float4*)(nb + (size_t)j * ND);
  double a0 = 0.0, a1 = 0.0, a2 = 0.0, a3 = 0.0;
#pragma unroll
  for (int d4 = 0; d4 < ND / 4; ++d4) {
    float4 n4 = nrow[d4];
    double d0 = qs[d4 * 4 + 0] - (double)n4.x;
    double d1 = qs[d4 * 4 + 1] - (double)n4.y;
    double d2 = qs[d4 * 4 + 2] - (double)n4.z;
    double d3 = qs[d4 * 4 + 3] - (double)n4.w;
    a0 += d0 * d0; a1 += d1 * d1; a2 += d2 * d2; a3 += d3 * d3;
  }
  s_out[(size_t)p * NN + j] =
      (double)gum[(size_t)p * NN + j] - ((a0 + a1) + (a2 + a3));
}

__global__ __launch_bounds__(256) void k_bsum(const double* __restrict__ s,
                                              double* __restrict__ Bq) {
  int b = blockIdx.x;
  int p = b >> 4, jc = (b >> 2) & 3, iq = b & 3;
  __shared__ double ss[256];
  int tid = threadIdx.x;
  ss[tid] = s[(size_t)p * NN + iq * 256 + tid];
  __syncthreads();
  double sj = s[(size_t)p * NN + jc * 256 + tid];
  double a0 = 0.0, a1 = 0.0, a2 = 0.0, a3 = 0.0;
#pragma unroll 4
  for (int i = 0; i < 256; i += 4) {
    a0 += fabs(sj - ss[i + 0]);
    a1 += fabs(sj - ss[i + 1]);
    a2 += fabs(sj - ss[i + 2]);
    a3 += fabs(sj - ss[i + 3]);
  }
  Bq[((size_t)iq * NP + p) * NN + jc * 256 + tid] = (a0 + a1) + (a2 + a3);
}

__global__ __launch_bounds__(256) void k_soft(const double* __restrict__ s,
                                              const double* __restrict__ Bq,
                                              float* __restrict__ out) {
  int p = blockIdx.x;
  int tid = threadIdx.x;
  int wave = tid >> 6, lane = tid & 63;
  const size_t QS = (size_t)NP * NN;
  size_t base = (size_t)p * NN;
  double sj[4], bj[4];
  float acc[4];
#pragma unroll
  for (int k = 0; k < 4; ++k) {
    size_t idx = base + tid + k * 256;
    sj[k] = s[idx];
    bj[k] = (Bq[idx] + Bq[QS + idx]) + (Bq[2 * QS + idx] + Bq[3 * QS + idx]);
    acc[k] = 0.f;
  }
  __shared__ float redm[KTOP][4];
  __shared__ float redz[KTOP][4];
  float mx[KTOP];
#pragma unroll
  for (int r = 0; r < KTOP; ++r) {
    double cr = (double)(1023 - 2 * r);
    float mv = -3.4e38f;
#pragma unroll
    for (int k = 0; k < 4; ++k) mv = fmaxf(mv, (float)fma(cr, sj[k], -bj[k]));
    mx[r] = mv;
  }
#pragma unroll
  for (int off = 32; off; off >>= 1) {
#pragma unroll
    for (int r = 0; r < KTOP; ++r)
      mx[r] = fmaxf(mx[r], __shfl_down(mx[r], off, 64));
  }
  if (lane == 0) {
#pragma unroll
    for (int r = 0; r < KTOP; ++r) redm[r][wave] = mx[r];
  }
  __syncthreads();
  float mf[KTOP];
#pragma unroll
  for (int r = 0; r < KTOP; ++r)
    mf[r] = fmaxf(fmaxf(redm[r][0], redm[r][1]),
                  fmaxf(redm[r][2], redm[r][3]));
  float zz[KTOP];
#pragma unroll
  for (int r = 0; r < KTOP; ++r) {
    double cr = (double)(1023 - 2 * r);
    double md = (double)mf[r];
    float z = 0.f;
#pragma unroll
    for (int k = 0; k < 4; ++k)
      z += __expf((float)(fma(cr, sj[k], -bj[k]) - md));
    zz[r] = z;
  }
#pragma unroll
  for (int off = 32; off; off >>= 1) {
#pragma unroll
    for (int r = 0; r < KTOP; ++r) zz[r] += __shfl_down(zz[r], off, 64);
  }
  if (lane == 0) {
#pragma unroll
    for (int r = 0; r < KTOP; ++r) redz[r][wave] = zz[r];
  }
  __syncthreads();
#pragma unroll
  for (int r = 0; r < KTOP; ++r) {
    double cr = (double)(1023 - 2 * r);
    double md = (double)mf[r];
    float iZ = 1.0f / ((redz[r][0] + redz[r][1]) + (redz[r][2] + redz[r][3]));
#pragma unroll
    for (int k = 0; k < 4; ++k)
      acc[k] += __expf((float)(fma(cr, sj[k], -bj[k]) - md)) * iZ;
  }
#pragma unroll
  for (int k = 0; k < 4; ++k) out[base + tid + k * 256] = acc[k];
}

extern "C" void kernel_launch(void* const* d_in, const int* in_sizes, int n_in,
                              void* d_out, int out_size, void* d_ws, size_t ws_size,
                              hipStream_t stream) {
  const float* q   = (const float*)d_in[0];   // [32,128]
  const float* nb  = (const float*)d_in[1];   // [1024,128]
  const float* gum = (const float*)d_in[2];   // [2,32,1024]
  float* out = (float*)d_out;                 // [2,32,1024]

  char* ws = (char*)d_ws;
  double* s  = (double*)ws;                              // 512 KiB
  double* Bq = (double*)(ws + (size_t)NP * NN * 8);      // 4 x 512 KiB

  void* args[] = {(void*)&q, (void*)&nb, (void*)&gum,
                  (void*)&s, (void*)&Bq, (void*)&out};
  hipError_t err = hipLaunchCooperativeKernel(
      reinterpret_cast<void*>(k_fused), dim3(1024), dim3(256), args, 0, stream);
  if (err != hipSuccess) {
    // fallback: R6 three-dispatch path (bit-identical)
    k_scores<<<256, 256, 0, stream>>>(q, nb, gum, s);
    k_bsum<<<1024, 256, 0, stream>>>(s, Bq);
    k_soft<<<NP, 256, 0, stream>>>(s, Bq, out);
  }
}

// Round 5
// 96.954 us; speedup vs baseline: 5.0016x; 5.0016x over previous
//
#include <hip/hip_runtime.h>

// DKNN via NeuralSort relaxation — round 8 (fold scores into bsum, no coop).
// query [32,128] f32, neighbors [1024,128] f32, gumbel [2,32,1024] f32.
// out [2,32,1024] f32 = sum of first K=16 rows of relaxed perm matrix.
//
// Numerics FROZEN (absmax pinned at 0.0234375, bf16 compare). The score
// expression (a0..a3 stride-4 f64 chain, (a0+a1)+(a2+a3) combine), the
// B quarter-sum body, Bq layout, and k_soft are byte-for-byte R6 =>
// bitwise-identical output.
//
// R7 post-mortem: grid.sync() on 8 XCDs costs ~200us each (433us kernel) —
// cooperative fusion is dead. R6 accounting: 75.7 = 40 (harness 256MiB
// poison-fill, untouchable) + ~11 kernel work + ~25 dispatch gaps (3
// dependent boundaries x ~7-8us). R8 removes one boundary by recomputing
// scores redundantly inside the 1024-block B kernel: each thread computes
// its iq-quarter score (-> LDS) and jc-quarter score (-> register) with the
// exact k_scores chain; blocks with iq==jc write s to global for k_soft.
// Phase B keeps 4 blocks/CU occupancy (the R5 fusion mistake avoided).

constexpr int NN = 1024;   // neighbors
constexpr int ND = 128;    // dims
constexpr int NP = 64;     // samples(2) * queries(32)
constexpr int KTOP = 16;

// ---------------------------------------------------------------- kernel 1
// Fused scores+B. grid = 64p * 4jc * 4iq = 1024 blocks x 256 thr.
__global__ __launch_bounds__(256) void k_sb2(const float* __restrict__ q,
                                             const float* __restrict__ nb,
                                             const float* __restrict__ gum,
                                             double* __restrict__ s_out,
                                             double* __restrict__ Bq) {
  int b = blockIdx.x;
  int p = b >> 4, jc = (b >> 2) & 3, iq = b & 3;
  int m = p & 31;
  __shared__ double qs[ND];
  __shared__ double ss[256];
  int tid = threadIdx.x;
  if (tid < ND) qs[tid] = (double)q[m * ND + tid];
  __syncthreads();

  // score for this block's iq-quarter element (exact R3/R6 k_scores chain)
  double s_iq;
  {
    int j = iq * 256 + tid;
    const float4* nrow = (const float4*)(nb + (size_t)j * ND);
    double a0 = 0.0, a1 = 0.0, a2 = 0.0, a3 = 0.0;
#pragma unroll 8
    for (int d4 = 0; d4 < ND / 4; ++d4) {
      float4 n4 = nrow[d4];
      double d0 = qs[d4 * 4 + 0] - (double)n4.x;
      double d1 = qs[d4 * 4 + 1] - (double)n4.y;
      double d2 = qs[d4 * 4 + 2] - (double)n4.z;
      double d3 = qs[d4 * 4 + 3] - (double)n4.w;
      a0 += d0 * d0; a1 += d1 * d1; a2 += d2 * d2; a3 += d3 * d3;
    }
    s_iq = (double)gum[(size_t)p * NN + j] - ((a0 + a1) + (a2 + a3));
  }
  ss[tid] = s_iq;

  // score for this thread's own j (jc-quarter), same exact chain
  int j = jc * 256 + tid;
  double sj;
  {
    const float4* nrow = (const float4*)(nb + (size_t)j * ND);
    double a0 = 0.0, a1 = 0.0, a2 = 0.0, a3 = 0.0;
#pragma unroll 8
    for (int d4 = 0; d4 < ND / 4; ++d4) {
      float4 n4 = nrow[d4];
      double d0 = qs[d4 * 4 + 0] - (double)n4.x;
      double d1 = qs[d4 * 4 + 1] - (double)n4.y;
      double d2 = qs[d4 * 4 + 2] - (double)n4.z;
      double d3 = qs[d4 * 4 + 3] - (double)n4.w;
      a0 += d0 * d0; a1 += d1 * d1; a2 += d2 * d2; a3 += d3 * d3;
    }
    sj = (double)gum[(size_t)p * NN + j] - ((a0 + a1) + (a2 + a3));
  }
  // one block per (p, jc) owns the global s write for k_soft
  if (iq == jc) s_out[(size_t)p * NN + j] = sj;
  __syncthreads();

  // ---- phase B: exact R6 k_bsum body ----
  double a0 = 0.0, a1 = 0.0, a2 = 0.0, a3 = 0.0;
#pragma unroll 4
  for (int i = 0; i < 256; i += 4) {
    a0 += fabs(sj - ss[i + 0]);
    a1 += fabs(sj - ss[i + 1]);
    a2 += fabs(sj - ss[i + 2]);
    a3 += fabs(sj - ss[i + 3]);
  }
  Bq[((size_t)iq * NP + p) * NN + jc * 256 + tid] = (a0 + a1) + (a2 + a3);
}

// ---------------------------------------------------------------- kernel 2
// Softmax-topk, exact R6 k_soft (2 barriers, batched reductions).
__global__ __launch_bounds__(256) void k_soft(const double* __restrict__ s,
                                              const double* __restrict__ Bq,
                                              float* __restrict__ out) {
  int p = blockIdx.x;
  int tid = threadIdx.x;
  int wave = tid >> 6, lane = tid & 63;
  const size_t QS = (size_t)NP * NN;
  size_t base = (size_t)p * NN;
  double sj[4], bj[4];
  float acc[4];
#pragma unroll
  for (int k = 0; k < 4; ++k) {
    size_t idx = base + tid + k * 256;
    sj[k] = s[idx];
    bj[k] = (Bq[idx] + Bq[QS + idx]) + (Bq[2 * QS + idx] + Bq[3 * QS + idx]);
    acc[k] = 0.f;
  }
  __shared__ float redm[KTOP][4];
  __shared__ float redz[KTOP][4];
  // pass 1: per-thread maxes for all 16 ranks, one batched reduction
  float mx[KTOP];
#pragma unroll
  for (int r = 0; r < KTOP; ++r) {
    double cr = (double)(1023 - 2 * r);
    float mv = -3.4e38f;
#pragma unroll
    for (int k = 0; k < 4; ++k) mv = fmaxf(mv, (float)fma(cr, sj[k], -bj[k]));
    mx[r] = mv;
  }
#pragma unroll
  for (int off = 32; off; off >>= 1) {
#pragma unroll
    for (int r = 0; r < KTOP; ++r)
      mx[r] = fmaxf(mx[r], __shfl_down(mx[r], off, 64));
  }
  if (lane == 0) {
#pragma unroll
    for (int r = 0; r < KTOP; ++r) redm[r][wave] = mx[r];
  }
  __syncthreads();
  float mf[KTOP];
#pragma unroll
  for (int r = 0; r < KTOP; ++r)
    mf[r] = fmaxf(fmaxf(redm[r][0], redm[r][1]),
                  fmaxf(redm[r][2], redm[r][3]));
  // pass 2: per-thread Z partials for all 16 ranks, one batched reduction
  float zz[KTOP];
#pragma unroll
  for (int r = 0; r < KTOP; ++r) {
    double cr = (double)(1023 - 2 * r);
    double md = (double)mf[r];
    float z = 0.f;
#pragma unroll
    for (int k = 0; k < 4; ++k)
      z += __expf((float)(fma(cr, sj[k], -bj[k]) - md));
    zz[r] = z;
  }
#pragma unroll
  for (int off = 32; off; off >>= 1) {
#pragma unroll
    for (int r = 0; r < KTOP; ++r) zz[r] += __shfl_down(zz[r], off, 64);
  }
  if (lane == 0) {
#pragma unroll
    for (int r = 0; r < KTOP; ++r) redz[r][wave] = zz[r];
  }
  __syncthreads();
  // pass 3: accumulate in original r order (bitwise-identical acc)
#pragma unroll
  for (int r = 0; r < KTOP; ++r) {
    double cr = (double)(1023 - 2 * r);
    double md = (double)mf[r];
    float iZ = 1.0f / ((redz[r][0] + redz[r][1]) + (redz[r][2] + redz[r][3]));
#pragma unroll
    for (int k = 0; k < 4; ++k)
      acc[k] += __expf((float)(fma(cr, sj[k], -bj[k]) - md)) * iZ;
  }
#pragma unroll
  for (int k = 0; k < 4; ++k) out[base + tid + k * 256] = acc[k];
}

extern "C" void kernel_launch(void* const* d_in, const int* in_sizes, int n_in,
                              void* d_out, int out_size, void* d_ws, size_t ws_size,
                              hipStream_t stream) {
  const float* q   = (const float*)d_in[0];   // [32,128]
  const float* nb  = (const float*)d_in[1];   // [1024,128]
  const float* gum = (const float*)d_in[2];   // [2,32,1024]
  float* out = (float*)d_out;                 // [2,32,1024]

  char* ws = (char*)d_ws;
  double* s  = (double*)ws;                              // 512 KiB
  double* Bq = (double*)(ws + (size_t)NP * NN * 8);      // 4 x 512 KiB

  k_sb2<<<1024, 256, 0, stream>>>(q, nb, gum, s, Bq);
  k_soft<<<NP, 256, 0, stream>>>(s, Bq, out);
}

// Round 6
// 86.313 us; speedup vs baseline: 5.6182x; 1.1233x over previous
//
#include <hip/hip_runtime.h>

// DKNN via NeuralSort relaxation — round 9 (transaction-aware fusion).
// query [32,128] f32, neighbors [1024,128] f32, gumbel [2,32,1024] f32.
// out [2,32,1024] f32 = sum of first K=16 rows of relaxed perm matrix.
//
// Numerics FROZEN (absmax pinned at 0.0234375, bf16 compare). Score chain,
// per-quarter a0..a3 stride-4 B sums, (q0+q1)+(q2+q3) combine, and the
// k_soft reduction trees are the exact R6 orders => bitwise-identical.
//
// R8 post-mortem: score chains are TA line-transaction bound (lane-stride
// 512B float4 loads = 64 lines/wave-instr). R8 ran 8x the line count of
// R6's k_scores -> ~30us. Lesson: count lines/CU, not bytes.
//
// R9 structure: k_sbig = 256 blocks (p,jc) x 1024 threads.
//  - score phase: thread t computes the chain for i=t (once per block, 4x
//    device redundancy — the minimum for block-local B). Time-chunked so
//    only 4 waves stream nb at a time: L1 working set 16KB -> each of the
//    8192 lines/CU fetched once (~3.4us). Aggregate L2: 256x512KB=128MB
//    / 34.5TB/s = 3.7us — consistent.
//  - B phase: thread t = (iq,jj) computes quarter-iq sum for j=jc*256+jj
//    from LDS (broadcast reads), 16 waves/CU on ALL 256 CUs (~3.4us),
//    then combines quarters via LDS with the frozen order and writes the
//    combined B (k_soft now loads 1 value instead of 4+3 adds).
// k_soft: exact R6 body, bj[k] = B[idx] (same bits).

constexpr int NN = 1024;   // neighbors
constexpr int ND = 128;    // dims
constexpr int NP = 64;     // samples(2) * queries(32)
constexpr int KTOP = 16;

// ---------------------------------------------------------------- kernel 1
// Fused scores + B. grid = 64p * 4jc = 256 blocks x 1024 thr (1 block/CU).
__global__ __launch_bounds__(1024, 4) void k_sbig(
    const float* __restrict__ q, const float* __restrict__ nb,
    const float* __restrict__ gum, double* __restrict__ s_out,
    double* __restrict__ b_out) {
  int b = blockIdx.x;
  int p = b >> 2, jc = b & 3;
  int m = p & 31;
  __shared__ double qs[ND];
  __shared__ double ss[NN];
  __shared__ double qarr[NN];
  int tid = threadIdx.x;
  if (tid < ND) qs[tid] = (double)q[m * ND + tid];
  __syncthreads();

  // ---- phase S: scores, chunked 4x (4 waves streaming at a time keeps the
  // L1 working set at 16KB so each nb line is fetched exactly once).
  int myc = tid >> 8;  // wave-uniform (wave = 64 | 256-boundaries)
  for (int c = 0; c < 4; ++c) {
    if (myc == c) {
      int i = tid;
      const float4* nrow = (const float4*)(nb + (size_t)i * ND);
      double a0 = 0.0, a1 = 0.0, a2 = 0.0, a3 = 0.0;
#pragma unroll 4
      for (int d4 = 0; d4 < ND / 4; ++d4) {
        float4 n4 = nrow[d4];
        double d0 = qs[d4 * 4 + 0] - (double)n4.x;
        double d1 = qs[d4 * 4 + 1] - (double)n4.y;
        double d2 = qs[d4 * 4 + 2] - (double)n4.z;
        double d3 = qs[d4 * 4 + 3] - (double)n4.w;
        a0 += d0 * d0; a1 += d1 * d1; a2 += d2 * d2; a3 += d3 * d3;
      }
      ss[i] = (double)gum[(size_t)p * NN + i] - ((a0 + a1) + (a2 + a3));
    }
    __syncthreads();
  }

  // ---- phase B: thread t = (iq = t>>8, jj = t&255) computes the quarter-iq
  // sum for j = jc*256+jj (exact R6 k_bsum inner loop; ss reads broadcast).
  int jj = tid & 255;
  int iq = tid >> 8;
  int j = jc * 256 + jj;
  double sj = ss[j];
  const double* sq = ss + iq * 256;
  double a0 = 0.0, a1 = 0.0, a2 = 0.0, a3 = 0.0;
#pragma unroll 4
  for (int i = 0; i < 256; i += 4) {
    a0 += fabs(sj - sq[i + 0]);
    a1 += fabs(sj - sq[i + 1]);
    a2 += fabs(sj - sq[i + 2]);
    a3 += fabs(sj - sq[i + 3]);
  }
  qarr[tid] = (a0 + a1) + (a2 + a3);
  __syncthreads();

  // ---- combine quarters (frozen (q0+q1)+(q2+q3) order) + write s, B.
  if (tid < 256) {
    double bjv = (qarr[tid] + qarr[tid + 256]) +
                 (qarr[tid + 512] + qarr[tid + 768]);
    size_t gidx = (size_t)p * NN + jc * 256 + tid;
    b_out[gidx] = bjv;
    s_out[gidx] = ss[jc * 256 + tid];
  }
}

// ---------------------------------------------------------------- kernel 2
// Softmax-topk, exact R6 k_soft (2 barriers, batched reductions); bj is a
// single load of the pre-combined B (identical bits to R6's 4-load combine).
__global__ __launch_bounds__(256) void k_soft(const double* __restrict__ s,
                                              const double* __restrict__ B,
                                              float* __restrict__ out) {
  int p = blockIdx.x;
  int tid = threadIdx.x;
  int wave = tid >> 6, lane = tid & 63;
  size_t base = (size_t)p * NN;
  double sj[4], bj[4];
  float acc[4];
#pragma unroll
  for (int k = 0; k < 4; ++k) {
    size_t idx = base + tid + k * 256;
    sj[k] = s[idx];
    bj[k] = B[idx];
    acc[k] = 0.f;
  }
  __shared__ float redm[KTOP][4];
  __shared__ float redz[KTOP][4];
  // pass 1: per-thread maxes for all 16 ranks, one batched reduction
  float mx[KTOP];
#pragma unroll
  for (int r = 0; r < KTOP; ++r) {
    double cr = (double)(1023 - 2 * r);
    float mv = -3.4e38f;
#pragma unroll
    for (int k = 0; k < 4; ++k) mv = fmaxf(mv, (float)fma(cr, sj[k], -bj[k]));
    mx[r] = mv;
  }
#pragma unroll
  for (int off = 32; off; off >>= 1) {
#pragma unroll
    for (int r = 0; r < KTOP; ++r)
      mx[r] = fmaxf(mx[r], __shfl_down(mx[r], off, 64));
  }
  if (lane == 0) {
#pragma unroll
    for (int r = 0; r < KTOP; ++r) redm[r][wave] = mx[r];
  }
  __syncthreads();
  float mf[KTOP];
#pragma unroll
  for (int r = 0; r < KTOP; ++r)
    mf[r] = fmaxf(fmaxf(redm[r][0], redm[r][1]),
                  fmaxf(redm[r][2], redm[r][3]));
  // pass 2: per-thread Z partials for all 16 ranks, one batched reduction
  float zz[KTOP];
#pragma unroll
  for (int r = 0; r < KTOP; ++r) {
    double cr = (double)(1023 - 2 * r);
    double md = (double)mf[r];
    float z = 0.f;
#pragma unroll
    for (int k = 0; k < 4; ++k)
      z += __expf((float)(fma(cr, sj[k], -bj[k]) - md));
    zz[r] = z;
  }
#pragma unroll
  for (int off = 32; off; off >>= 1) {
#pragma unroll
    for (int r = 0; r < KTOP; ++r) zz[r] += __shfl_down(zz[r], off, 64);
  }
  if (lane == 0) {
#pragma unroll
    for (int r = 0; r < KTOP; ++r) redz[r][wave] = zz[r];
  }
  __syncthreads();
  // pass 3: accumulate in original r order (bitwise-identical acc)
#pragma unroll
  for (int r = 0; r < KTOP; ++r) {
    double cr = (double)(1023 - 2 * r);
    double md = (double)mf[r];
    float iZ = 1.0f / ((redz[r][0] + redz[r][1]) + (redz[r][2] + redz[r][3]));
#pragma unroll
    for (int k = 0; k < 4; ++k)
      acc[k] += __expf((float)(fma(cr, sj[k], -bj[k]) - md)) * iZ;
  }
#pragma unroll
  for (int k = 0; k < 4; ++k) out[base + tid + k * 256] = acc[k];
}

extern "C" void kernel_launch(void* const* d_in, const int* in_sizes, int n_in,
                              void* d_out, int out_size, void* d_ws, size_t ws_size,
                              hipStream_t stream) {
  const float* q   = (const float*)d_in[0];   // [32,128]
  const float* nb  = (const float*)d_in[1];   // [1024,128]
  const float* gum = (const float*)d_in[2];   // [2,32,1024]
  float* out = (float*)d_out;                 // [2,32,1024]

  char* ws = (char*)d_ws;
  double* s = (double*)ws;                          // 512 KiB
  double* B = (double*)(ws + (size_t)NP * NN * 8);  // 512 KiB

  k_sbig<<<256, 1024, 0, stream>>>(q, nb, gum, s, B);
  k_soft<<<NP, 256, 0, stream>>>(s, B, out);
}

// Round 8
// 84.052 us; speedup vs baseline: 5.7693x; 1.0269x over previous
//
#include <hip/hip_runtime.h>

// DKNN via NeuralSort relaxation — round 10 resubmit (R9 minus chunk gate).
// Previous bench attempt failed with an infra error (container failed
// twice) — no counters, no verdict. Kernel is byte-identical to R10.
//
// query [32,128] f32, neighbors [1024,128] f32, gumbel [2,32,1024] f32.
// out [2,32,1024] f32 = sum of first K=16 rows of relaxed perm matrix.
//
// Numerics FROZEN (absmax pinned at 0.0234375, bf16 compare). Score chain,
// per-quarter a0..a3 stride-4 B sums, (q0+q1)+(q2+q3) combine, and the
// k_soft reduction trees are the exact R6/R9 orders => bitwise-identical.
//
// R9 post-mortem: chunking phase S to protect L1 left 1 wave/SIMD active
// per chunk x 4 sequential chunks (the R5 latency-exposure mistake) ->
// k_sbig ~27us. Unchunked: 16 waves/block = 4 waves/SIMD hide L1/L2
// latency; per-CU traffic 512KB streamed from L2-resident nb (~8192 line
// fills ~3.4us), f64 issue ~2.1us -> phase S ~3.5us. Phase B issue-bound
// at full device: 4 waves/SIMD x 512 f64 ops x 4cyc ~ 3.4us. B work
// (134M f64 ops) needs all 256 CUs -> the (p,jc) x 1024-thread split is
// the minimal-redundancy layout that keeps B on the whole device.

constexpr int NN = 1024;   // neighbors
constexpr int ND = 128;    // dims
constexpr int NP = 64;     // samples(2) * queries(32)
constexpr int KTOP = 16;

// ---------------------------------------------------------------- kernel 1
// Fused scores + B. grid = 64p * 4jc = 256 blocks x 1024 thr (1 block/CU).
__global__ __launch_bounds__(1024, 4) void k_sbig(
    const float* __restrict__ q, const float* __restrict__ nb,
    const float* __restrict__ gum, double* __restrict__ s_out,
    double* __restrict__ b_out) {
  int b = blockIdx.x;
  int p = b >> 2, jc = b & 3;
  int m = p & 31;
  __shared__ double qs[ND];
  __shared__ double ss[NN];
  __shared__ double qarr[NN];
  int tid = threadIdx.x;
  if (tid < ND) qs[tid] = (double)q[m * ND + tid];
  __syncthreads();

  // ---- phase S: all 1024 chains at once (4 waves/SIMD hide latency).
  {
    int i = tid;
    const float4* nrow = (const float4*)(nb + (size_t)i * ND);
    double a0 = 0.0, a1 = 0.0, a2 = 0.0, a3 = 0.0;
#pragma unroll 4
    for (int d4 = 0; d4 < ND / 4; ++d4) {
      float4 n4 = nrow[d4];
      double d0 = qs[d4 * 4 + 0] - (double)n4.x;
      double d1 = qs[d4 * 4 + 1] - (double)n4.y;
      double d2 = qs[d4 * 4 + 2] - (double)n4.z;
      double d3 = qs[d4 * 4 + 3] - (double)n4.w;
      a0 += d0 * d0; a1 += d1 * d1; a2 += d2 * d2; a3 += d3 * d3;
    }
    ss[i] = (double)gum[(size_t)p * NN + i] - ((a0 + a1) + (a2 + a3));
  }
  __syncthreads();

  // ---- phase B: thread t = (iq = t>>8, jj = t&255) computes the quarter-iq
  // sum for j = jc*256+jj (exact R6 k_bsum inner loop; sq reads broadcast).
  int jj = tid & 255;
  int iq = tid >> 8;
  int j = jc * 256 + jj;
  double sj = ss[j];
  const double* sq = ss + iq * 256;
  double a0 = 0.0, a1 = 0.0, a2 = 0.0, a3 = 0.0;
#pragma unroll 4
  for (int i = 0; i < 256; i += 4) {
    a0 += fabs(sj - sq[i + 0]);
    a1 += fabs(sj - sq[i + 1]);
    a2 += fabs(sj - sq[i + 2]);
    a3 += fabs(sj - sq[i + 3]);
  }
  qarr[tid] = (a0 + a1) + (a2 + a3);
  __syncthreads();

  // ---- combine quarters (frozen (q0+q1)+(q2+q3) order) + write s, B.
  if (tid < 256) {
    double bjv = (qarr[tid] + qarr[tid + 256]) +
                 (qarr[tid + 512] + qarr[tid + 768]);
    size_t gidx = (size_t)p * NN + jc * 256 + tid;
    b_out[gidx] = bjv;
    s_out[gidx] = ss[jc * 256 + tid];
  }
}

// ---------------------------------------------------------------- kernel 2
// Softmax-topk, exact R6 k_soft (2 barriers, batched reductions); bj is a
// single load of the pre-combined B (identical bits to R6's 4-load combine).
__global__ __launch_bounds__(256) void k_soft(const double* __restrict__ s,
                                              const double* __restrict__ B,
                                              float* __restrict__ out) {
  int p = blockIdx.x;
  int tid = threadIdx.x;
  int wave = tid >> 6, lane = tid & 63;
  size_t base = (size_t)p * NN;
  double sj[4], bj[4];
  float acc[4];
#pragma unroll
  for (int k = 0; k < 4; ++k) {
    size_t idx = base + tid + k * 256;
    sj[k] = s[idx];
    bj[k] = B[idx];
    acc[k] = 0.f;
  }
  __shared__ float redm[KTOP][4];
  __shared__ float redz[KTOP][4];
  // pass 1: per-thread maxes for all 16 ranks, one batched reduction
  float mx[KTOP];
#pragma unroll
  for (int r = 0; r < KTOP; ++r) {
    double cr = (double)(1023 - 2 * r);
    float mv = -3.4e38f;
#pragma unroll
    for (int k = 0; k < 4; ++k) mv = fmaxf(mv, (float)fma(cr, sj[k], -bj[k]));
    mx[r] = mv;
  }
#pragma unroll
  for (int off = 32; off; off >>= 1) {
#pragma unroll
    for (int r = 0; r < KTOP; ++r)
      mx[r] = fmaxf(mx[r], __shfl_down(mx[r], off, 64));
  }
  if (lane == 0) {
#pragma unroll
    for (int r = 0; r < KTOP; ++r) redm[r][wave] = mx[r];
  }
  __syncthreads();
  float mf[KTOP];
#pragma unroll
  for (int r = 0; r < KTOP; ++r)
    mf[r] = fmaxf(fmaxf(redm[r][0], redm[r][1]),
                  fmaxf(redm[r][2], redm[r][3]));
  // pass 2: per-thread Z partials for all 16 ranks, one batched reduction
  float zz[KTOP];
#pragma unroll
  for (int r = 0; r < KTOP; ++r) {
    double cr = (double)(1023 - 2 * r);
    double md = (double)mf[r];
    float z = 0.f;
#pragma unroll
    for (int k = 0; k < 4; ++k)
      z += __expf((float)(fma(cr, sj[k], -bj[k]) - md));
    zz[r] = z;
  }
#pragma unroll
  for (int off = 32; off; off >>= 1) {
#pragma unroll
    for (int r = 0; r < KTOP; ++r) zz[r] += __shfl_down(zz[r], off, 64);
  }
  if (lane == 0) {
#pragma unroll
    for (int r = 0; r < KTOP; ++r) redz[r][wave] = zz[r];
  }
  __syncthreads();
  // pass 3: accumulate in original r order (bitwise-identical acc)
#pragma unroll
  for (int r = 0; r < KTOP; ++r) {
    double cr = (double)(1023 - 2 * r);
    double md = (double)mf[r];
    float iZ = 1.0f / ((redz[r][0] + redz[r][1]) + (redz[r][2] + redz[r][3]));
#pragma unroll
    for (int k = 0; k < 4; ++k)
      acc[k] += __expf((float)(fma(cr, sj[k], -bj[k]) - md)) * iZ;
  }
#pragma unroll
  for (int k = 0; k < 4; ++k) out[base + tid + k * 256] = acc[k];
}

extern "C" void kernel_launch(void* const* d_in, const int* in_sizes, int n_in,
                              void* d_out, int out_size, void* d_ws, size_t ws_size,
                              hipStream_t stream) {
  const float* q   = (const float*)d_in[0];   // [32,128]
  const float* nb  = (const float*)d_in[1];   // [1024,128]
  const float* gum = (const float*)d_in[2];   // [2,32,1024]
  float* out = (float*)d_out;                 // [2,32,1024]

  char* ws = (char*)d_ws;
  double* s = (double*)ws;                          // 512 KiB
  double* B = (double*)(ws + (size_t)NP * NN * 8);  // 512 KiB

  k_sbig<<<256, 1024, 0, stream>>>(q, nb, gum, s, B);
  k_soft<<<NP, 256, 0, stream>>>(s, B, out);
}